// Round 7
// baseline (1778.977 us; speedup 1.0000x reference)
//
#include <hip/hip_runtime.h>
#include <hip/hip_bf16.h>

#define N_NODES   20000
#define N_EDGES   320000
#define DIM       256
#define N_GRAPHS  64
#define N_CLASSES 10
// CSR = edges + 1 self-loop per node, unpadded (block loop uses clamp+zero-weight)
#define CSR_CAP   (N_EDGES + N_NODES)

typedef short  bf16x8 __attribute__((ext_vector_type(8)));
typedef float  f32x4  __attribute__((ext_vector_type(4)));
typedef float  f32x2  __attribute__((ext_vector_type(2)));

__device__ __forceinline__ float b2f(ushort u) {
    return __uint_as_float(((unsigned)u) << 16);
}
__device__ __forceinline__ ushort f2b(float f) {
    unsigned u = __float_as_uint(f);
    u += 0x7FFF + ((u >> 16) & 1);   // round-to-nearest-even
    return (ushort)(u >> 16);
}
// float -> fp8 e4m3 (OCP on gfx950), single value in byte 0
__device__ __forceinline__ unsigned char f2fp8(float f) {
    return (unsigned char)__builtin_amdgcn_cvt_pk_fp8_f32(f, f, 0, false);
}

// ---------------- setup kernels ----------------

__global__ void k_convert_x(const float* __restrict__ x, ushort* __restrict__ xb, int n4) {
    int i = blockIdx.x * blockDim.x + threadIdx.x;
    if (i >= n4) return;
    const float4 v = ((const float4*)x)[i];
    ushort4 o; o.x = f2b(v.x); o.y = f2b(v.y); o.z = f2b(v.z); o.w = f2b(v.w);
    ((ushort4*)xb)[i] = o;
}

// Wt[n*256+k] = bf16(W[k*256+n])
__global__ void k_wt(const float* __restrict__ W, ushort* __restrict__ Wt) {
    int i = blockIdx.x * blockDim.x + threadIdx.x;   // 65536
    int n = i >> 8, k = i & 255;
    Wt[i] = f2b(W[k * 256 + n]);
}

__global__ void k_deg(const int* __restrict__ dst, int* __restrict__ deg) {
    int e = blockIdx.x * 256 + threadIdx.x;
    if (e < N_EDGES) atomicAdd(&deg[dst[e]], 1);
}

__global__ void k_counts(const int* __restrict__ batch, int* __restrict__ counts) {
    int i = blockIdx.x * 256 + threadIdx.x;
    if (i < N_NODES) atomicAdd(&counts[batch[i]], 1);
}

// dinv = rsqrt(in_deg + 1) (self-loop); row length = deg+1 (self-loop), unpadded
__global__ void k_dinv_len(const int* __restrict__ deg, float* __restrict__ dinv,
                           int* __restrict__ rlen) {
    int i = blockIdx.x * 256 + threadIdx.x;
    if (i < N_NODES) {
        int d = deg[i];
        dinv[i] = rsqrtf((float)d + 1.0f);
        rlen[i] = d + 1;
    }
}

// single-block exclusive scan of rlen -> row_ptr[0..n]
__global__ void k_scan(const int* __restrict__ rlen, int* __restrict__ row_ptr, int n) {
    __shared__ int sh[1024];
    int tid = threadIdx.x;
    int off = 0;
    int nchunk = (n + 1023) >> 10;
    for (int c = 0; c < nchunk; ++c) {
        int i = (c << 10) + tid;
        int v = (i < n) ? rlen[i] : 0;
        sh[tid] = v;
        __syncthreads();
        for (int s = 1; s < 1024; s <<= 1) {
            int t = (tid >= s) ? sh[tid - s] : 0;
            __syncthreads();
            sh[tid] += t;
            __syncthreads();
        }
        if (i < n) row_ptr[i] = off + sh[tid] - v;   // exclusive
        off += sh[1023];
        __syncthreads();
    }
    if (tid == 0) row_ptr[n] = off;
}

// packed CSR entry: src node in low 16 bits, bf16 weight in high 16; drel = dst % 16.
// self-loop entry (i, dinv_i^2) -- runs before k_fill
__global__ void k_self(const int* __restrict__ row_ptr, int* __restrict__ fill,
                       const float* __restrict__ dinv, unsigned* __restrict__ csr,
                       unsigned char* __restrict__ drel) {
    int i = blockIdx.x * 256 + threadIdx.x;
    if (i >= N_NODES) return;
    int pos = atomicAdd(&fill[i], 1);
    int idx = row_ptr[i] + pos;
    csr[idx]  = ((unsigned)f2b(dinv[i] * dinv[i]) << 16) | (unsigned)i;
    drel[idx] = (unsigned char)(i & 15);
}

__global__ void k_fill(const int* __restrict__ src, const int* __restrict__ dst,
                       const int* __restrict__ row_ptr, int* __restrict__ fill,
                       const float* __restrict__ dinv, unsigned* __restrict__ csr,
                       unsigned char* __restrict__ drel) {
    int e = blockIdx.x * 256 + threadIdx.x;
    if (e >= N_EDGES) return;
    int s = src[e], d = dst[e];
    int pos = atomicAdd(&fill[d], 1);
    int idx = row_ptr[d] + pos;
    csr[idx]  = ((unsigned)f2b(dinv[s] * dinv[d]) << 16) | (unsigned)s;
    drel[idx] = (unsigned char)(d & 15);
}

// ---------------- GEMM: H8[M,256] = fp8(Xb[M,256] @ W), plain row-major ----------------
__global__ __launch_bounds__(256) void k_gemm(const ushort* __restrict__ Xb,
                                              const ushort* __restrict__ Wt,
                                              unsigned char* __restrict__ H8) {
    int wave = threadIdx.x >> 6;
    int lane = threadIdx.x & 63;
    int m0 = blockIdx.x * 16;
    int n0 = wave * 64;
    int rl = lane & 15;
    int kq = (lane >> 4) * 8;

    const ushort* aptr = Xb + (size_t)(m0 + rl) * DIM + kq;
    f32x4 acc[4] = {};

#pragma unroll
    for (int kk = 0; kk < 8; ++kk) {
        int k0 = kk * 32;
        bf16x8 a = *(const bf16x8*)(aptr + k0);
#pragma unroll
        for (int nb = 0; nb < 4; ++nb) {
            const ushort* bptr = Wt + (size_t)(n0 + nb * 16 + rl) * DIM + k0 + kq;
            bf16x8 b = *(const bf16x8*)bptr;
            acc[nb] = __builtin_amdgcn_mfma_f32_16x16x32_bf16(a, b, acc[nb], 0, 0, 0);
        }
    }
    int crow = m0 + (lane >> 4) * 4;
    int ccol = n0 + rl;
#pragma unroll
    for (int nb = 0; nb < 4; ++nb)
#pragma unroll
        for (int r = 0; r < 4; ++r)
            H8[(size_t)(crow + r) * DIM + ccol + nb * 16] = f2fp8(acc[nb][r]);
}

// ---------------- aggregation: block-level LDS SpMM ----------------
// Block = 16 dst nodes + their contiguous CSR slice. 4 waves stride the slice
// 8 edges at a time. Per edge: one 64-lane dword gather of the full fp8 row
// (256 B coalesced, 4 lines). Accumulate fp32 in LDS via ds_add_f32, layout
// acc[d][k*64+lane] (feature 4*lane+k) -> banks = lane%32, 2-way = free.
// sched_barrier(0) forces all 8 gathers issued before any consumer — defeats
// the R1-R6 compiler pattern of serializing each gather behind vmcnt(0).
// mode 0: relu(acc+b) ; mode 1: relu(prev+acc+b) ; mode 2: atomicAdd pooled
__global__ __launch_bounds__(256, 4) void k_agg(
    const unsigned char* __restrict__ H8, const int* __restrict__ row_ptr,
    const unsigned* __restrict__ csr, const unsigned char* __restrict__ drel,
    const float* __restrict__ bias, const ushort* __restrict__ prev,
    ushort* __restrict__ outb, float* __restrict__ pooled,
    const int* __restrict__ batch, int mode) {
    __shared__ float acc[16 * 256];
    int tid = threadIdx.x;
    int wave = tid >> 6, lane = tid & 63;
    int nb = blockIdx.x * 16;

#pragma unroll
    for (int k = 0; k < 16; ++k) acc[tid + k * 256] = 0.0f;
    __syncthreads();

    int E0 = row_ptr[nb], E1 = row_ptr[nb + 16];

    for (int e = E0 + wave * 8; e < E1; e += 32) {
        unsigned m[8]; int dr[8]; float w[8];
#pragma unroll
        for (int j = 0; j < 8; ++j) {
            int idx = (e + j < E1) ? e + j : E1 - 1;
            m[j]  = csr[idx];
            dr[j] = drel[idx];
            w[j]  = (e + j < E1) ? b2f((ushort)(m[j] >> 16)) : 0.0f;
        }
        __builtin_amdgcn_sched_barrier(0);
        unsigned g[8];
#pragma unroll
        for (int j = 0; j < 8; ++j)
            g[j] = *(const unsigned*)(H8 + (size_t)(m[j] & 0xFFFF) * DIM + lane * 4);
        __builtin_amdgcn_sched_barrier(0);
#pragma unroll
        for (int j = 0; j < 8; ++j) {
            f32x2 lo = __builtin_amdgcn_cvt_pk_f32_fp8(g[j], false);
            f32x2 hi = __builtin_amdgcn_cvt_pk_f32_fp8(g[j], true);
            float* a = acc + dr[j] * 256;
            atomicAdd(a +   0 + lane, w[j] * lo[0]);
            atomicAdd(a +  64 + lane, w[j] * lo[1]);
            atomicAdd(a + 128 + lane, w[j] * hi[0]);
            atomicAdd(a + 192 + lane, w[j] * hi[1]);
        }
    }
    __syncthreads();

    // epilogue: wave handles 4 nodes; lane covers features 4*lane..4*lane+3
#pragma unroll
    for (int q = 0; q < 4; ++q) {
        int d = wave * 4 + q;
        int i = nb + d;
        float r0 = acc[d * 256 +   0 + lane];
        float r1 = acc[d * 256 +  64 + lane];
        float r2 = acc[d * 256 + 128 + lane];
        float r3 = acc[d * 256 + 192 + lane];
        int fo = lane * 4;
        const float4 bb = *(const float4*)(bias + fo);
        r0 += bb.x; r1 += bb.y; r2 += bb.z; r3 += bb.w;
        if (mode == 2) {
            int g = batch[i];
            float* p = pooled + (size_t)g * DIM + fo;
            atomicAdd(p + 0, r0); atomicAdd(p + 1, r1);
            atomicAdd(p + 2, r2); atomicAdd(p + 3, r3);
            continue;
        }
        if (mode == 1) {
            ushort4 pv = *(const ushort4*)(prev + (size_t)i * DIM + fo);
            r0 += b2f(pv.x); r1 += b2f(pv.y); r2 += b2f(pv.z); r3 += b2f(pv.w);
        }
        ushort4 o;
        o.x = f2b(fmaxf(r0, 0.f)); o.y = f2b(fmaxf(r1, 0.f));
        o.z = f2b(fmaxf(r2, 0.f)); o.w = f2b(fmaxf(r3, 0.f));
        *(ushort4*)(outb + (size_t)i * DIM + fo) = o;
    }
}

// ---------------- head: pooled mean -> logits -> log_softmax ----------------
__global__ void k_final(const float* __restrict__ pooled, const int* __restrict__ counts,
                        const float* __restrict__ Wc, const float* __restrict__ bc,
                        float* __restrict__ out) {
    int g = blockIdx.x, lane = threadIdx.x;   // 64 threads = 1 wave
    float inv = 1.0f / fmaxf((float)counts[g], 1.0f);
    const float4 pv = *(const float4*)(pooled + (size_t)g * DIM + lane * 4);
    float p0 = pv.x * inv, p1 = pv.y * inv, p2 = pv.z * inv, p3 = pv.w * inv;
    __shared__ float logits[N_CLASSES];
    int f = lane * 4;
    for (int c = 0; c < N_CLASSES; ++c) {
        float part = p0 * Wc[(f + 0) * N_CLASSES + c] + p1 * Wc[(f + 1) * N_CLASSES + c]
                   + p2 * Wc[(f + 2) * N_CLASSES + c] + p3 * Wc[(f + 3) * N_CLASSES + c];
        for (int s = 32; s > 0; s >>= 1) part += __shfl_down(part, s);
        if (lane == 0) logits[c] = part + bc[c];
    }
    __syncthreads();
    if (lane == 0) {
        float mx = logits[0];
        for (int c = 1; c < N_CLASSES; ++c) mx = fmaxf(mx, logits[c]);
        float se = 0.f;
        for (int c = 0; c < N_CLASSES; ++c) se += expf(logits[c] - mx);
        float lse = mx + logf(se);
        for (int c = 0; c < N_CLASSES; ++c) {
            out[g * N_CLASSES + c] = logits[c];
            out[N_GRAPHS * N_CLASSES + g * N_CLASSES + c] = logits[c] - lse;
        }
    }
}

// ---------------- launch ----------------
extern "C" void kernel_launch(void* const* d_in, const int* in_sizes, int n_in,
                              void* d_out, int out_size, void* d_ws, size_t ws_size,
                              hipStream_t stream) {
    const float* x    = (const float*)d_in[0];
    const int*   ei   = (const int*)d_in[1];
    const int*   src  = ei;
    const int*   dst  = ei + N_EDGES;
    const int*   batch= (const int*)d_in[2];
    const float* W1 = (const float*)d_in[3]; const float* b1 = (const float*)d_in[4];
    const float* W2 = (const float*)d_in[5]; const float* b2 = (const float*)d_in[6];
    const float* W3 = (const float*)d_in[7]; const float* b3 = (const float*)d_in[8];
    const float* Wc = (const float*)d_in[9]; const float* bc = (const float*)d_in[10];
    float* out = (float*)d_out;

    char* ws = (char*)d_ws;
    size_t off = 0;
    auto alloc = [&](size_t bytes) -> char* {
        char* p = ws + off;
        off = (off + bytes + 255) & ~(size_t)255;
        return p;
    };
    // ---- zeroed region (one memset) ----
    int*      deg     = (int*)alloc(N_NODES * 4);
    int*      fill    = (int*)alloc(N_NODES * 4);
    int*      counts  = (int*)alloc(N_GRAPHS * 4);
    float*    pooled  = (float*)alloc(N_GRAPHS * DIM * 4);
    size_t    zero_bytes = off;
    // ---- uninitialized scratch ----
    unsigned*      csr     = (unsigned*)alloc((size_t)CSR_CAP * 4);
    unsigned char* drel    = (unsigned char*)alloc((size_t)CSR_CAP);
    float*  dinv    = (float*)alloc(N_NODES * 4);
    int*    rlen    = (int*)alloc(N_NODES * 4);
    int*    row_ptr = (int*)alloc((N_NODES + 1) * 4);
    ushort* Wt1     = (ushort*)alloc(65536 * 2);
    ushort* Wt2     = (ushort*)alloc(65536 * 2);
    ushort* Wt3     = (ushort*)alloc(65536 * 2);
    ushort* xb      = (ushort*)alloc((size_t)N_NODES * DIM * 2);
    ushort* h1      = (ushort*)alloc((size_t)N_NODES * DIM * 2);
    unsigned char* h8 = (unsigned char*)alloc((size_t)N_NODES * DIM);

    hipMemsetAsync(d_ws, 0, zero_bytes, stream);

    k_convert_x<<<(N_NODES * DIM / 4 + 255) / 256, 256, 0, stream>>>(x, xb, N_NODES * DIM / 4);
    k_wt<<<256, 256, 0, stream>>>(W1, Wt1);
    k_wt<<<256, 256, 0, stream>>>(W2, Wt2);
    k_wt<<<256, 256, 0, stream>>>(W3, Wt3);
    k_deg<<<(N_EDGES + 255) / 256, 256, 0, stream>>>(dst, deg);
    k_counts<<<(N_NODES + 255) / 256, 256, 0, stream>>>(batch, counts);
    k_dinv_len<<<(N_NODES + 255) / 256, 256, 0, stream>>>(deg, dinv, rlen);
    k_scan<<<1, 1024, 0, stream>>>(rlen, row_ptr, N_NODES);
    k_self<<<(N_NODES + 255) / 256, 256, 0, stream>>>(row_ptr, fill, dinv, csr, drel);
    k_fill<<<(N_EDGES + 255) / 256, 256, 0, stream>>>(src, dst, row_ptr, fill, dinv, csr, drel);

    const int agg_grid = N_NODES / 16;   // 1250 blocks of 16 nodes

    // conv1: h1 = relu(agg(xb @ W1) + b1)
    k_gemm<<<N_NODES / 16, 256, 0, stream>>>(xb, Wt1, h8);
    k_agg<<<agg_grid, 256, 0, stream>>>(h8, row_ptr, csr, drel, b1,
                                        nullptr, h1, nullptr, nullptr, 0);
    // conv2: xb = relu(h1 + agg(h1 @ W2) + b2)
    k_gemm<<<N_NODES / 16, 256, 0, stream>>>(h1, Wt2, h8);
    k_agg<<<agg_grid, 256, 0, stream>>>(h8, row_ptr, csr, drel, b2,
                                        h1, xb, nullptr, nullptr, 1);
    // conv3: pooled += agg(xb @ W3) + b3
    k_gemm<<<N_NODES / 16, 256, 0, stream>>>(xb, Wt3, h8);
    k_agg<<<agg_grid, 256, 0, stream>>>(h8, row_ptr, csr, drel, b3,
                                        nullptr, nullptr, pooled, batch, 2);

    k_final<<<N_GRAPHS, 64, 0, stream>>>(pooled, counts, Wc, bc, out);
}

// Round 8
// 495.648 us; speedup vs baseline: 3.5892x; 3.5892x over previous
//
#include <hip/hip_runtime.h>
#include <hip/hip_bf16.h>

#define N_NODES   20000
#define N_EDGES   320000
#define DIM       256
#define N_GRAPHS  64
#define N_CLASSES 10
// CSR = edges + 1 self-loop per node, unpadded (every slot written exactly once)
#define CSR_CAP   (N_EDGES + N_NODES)

typedef short  bf16x8 __attribute__((ext_vector_type(8)));
typedef float  f32x4  __attribute__((ext_vector_type(4)));
typedef float  f32x2  __attribute__((ext_vector_type(2)));

__device__ __forceinline__ float b2f(ushort u) {
    return __uint_as_float(((unsigned)u) << 16);
}
__device__ __forceinline__ ushort f2b(float f) {
    unsigned u = __float_as_uint(f);
    u += 0x7FFF + ((u >> 16) & 1);   // round-to-nearest-even
    return (ushort)(u >> 16);
}
// float -> fp8 e4m3 (OCP on gfx950), single value in byte 0
__device__ __forceinline__ unsigned char f2fp8(float f) {
    return (unsigned char)__builtin_amdgcn_cvt_pk_fp8_f32(f, f, 0, false);
}

// ---------------- setup kernels ----------------

__global__ void k_convert_x(const float* __restrict__ x, ushort* __restrict__ xb, int n4) {
    int i = blockIdx.x * blockDim.x + threadIdx.x;
    if (i >= n4) return;
    const float4 v = ((const float4*)x)[i];
    ushort4 o; o.x = f2b(v.x); o.y = f2b(v.y); o.z = f2b(v.z); o.w = f2b(v.w);
    ((ushort4*)xb)[i] = o;
}

// Wt[n*256+k] = bf16(W[k*256+n])
__global__ void k_wt(const float* __restrict__ W, ushort* __restrict__ Wt) {
    int i = blockIdx.x * blockDim.x + threadIdx.x;   // 65536
    int n = i >> 8, k = i & 255;
    Wt[i] = f2b(W[k * 256 + n]);
}

__global__ void k_deg(const int* __restrict__ dst, int* __restrict__ deg) {
    int e = blockIdx.x * 256 + threadIdx.x;
    if (e < N_EDGES) atomicAdd(&deg[dst[e]], 1);
}

__global__ void k_counts(const int* __restrict__ batch, int* __restrict__ counts) {
    int i = blockIdx.x * 256 + threadIdx.x;
    if (i < N_NODES) atomicAdd(&counts[batch[i]], 1);
}

// dinv = rsqrt(in_deg + 1) (self-loop); row length = deg+1 (self-loop), unpadded
__global__ void k_dinv_len(const int* __restrict__ deg, float* __restrict__ dinv,
                           int* __restrict__ rlen) {
    int i = blockIdx.x * 256 + threadIdx.x;
    if (i < N_NODES) {
        int d = deg[i];
        dinv[i] = rsqrtf((float)d + 1.0f);
        rlen[i] = d + 1;
    }
}

// single-block exclusive scan of rlen -> row_ptr[0..n]
__global__ void k_scan(const int* __restrict__ rlen, int* __restrict__ row_ptr, int n) {
    __shared__ int sh[1024];
    int tid = threadIdx.x;
    int off = 0;
    int nchunk = (n + 1023) >> 10;
    for (int c = 0; c < nchunk; ++c) {
        int i = (c << 10) + tid;
        int v = (i < n) ? rlen[i] : 0;
        sh[tid] = v;
        __syncthreads();
        for (int s = 1; s < 1024; s <<= 1) {
            int t = (tid >= s) ? sh[tid - s] : 0;
            __syncthreads();
            sh[tid] += t;
            __syncthreads();
        }
        if (i < n) row_ptr[i] = off + sh[tid] - v;   // exclusive
        off += sh[1023];
        __syncthreads();
    }
    if (tid == 0) row_ptr[n] = off;
}

// packed CSR entry: src node in low 16 bits (N_NODES < 65536), bf16 weight in high 16.
// self-loop entry (i, dinv_i^2) -- runs before k_fill
__global__ void k_self(const int* __restrict__ row_ptr, int* __restrict__ fill,
                       const float* __restrict__ dinv, unsigned* __restrict__ csr) {
    int i = blockIdx.x * 256 + threadIdx.x;
    if (i >= N_NODES) return;
    int pos = atomicAdd(&fill[i], 1);
    csr[row_ptr[i] + pos] = ((unsigned)f2b(dinv[i] * dinv[i]) << 16) | (unsigned)i;
}

__global__ void k_fill(const int* __restrict__ src, const int* __restrict__ dst,
                       const int* __restrict__ row_ptr, int* __restrict__ fill,
                       const float* __restrict__ dinv, unsigned* __restrict__ csr) {
    int e = blockIdx.x * 256 + threadIdx.x;
    if (e >= N_EDGES) return;
    int s = src[e], d = dst[e];
    int pos = atomicAdd(&fill[d], 1);
    csr[row_ptr[d] + pos] = ((unsigned)f2b(dinv[s] * dinv[d]) << 16) | (unsigned)s;
}

// ---------------- GEMM: H8[M,256] = fp8(Xb[M,256] @ W), row-major ----------------
__global__ __launch_bounds__(256) void k_gemm(const ushort* __restrict__ Xb,
                                              const ushort* __restrict__ Wt,
                                              unsigned char* __restrict__ H8) {
    int wave = threadIdx.x >> 6;
    int lane = threadIdx.x & 63;
    int m0 = blockIdx.x * 16;
    int n0 = wave * 64;
    int rl = lane & 15;
    int kq = (lane >> 4) * 8;

    const ushort* aptr = Xb + (size_t)(m0 + rl) * DIM + kq;
    f32x4 acc[4] = {};

#pragma unroll
    for (int kk = 0; kk < 8; ++kk) {
        int k0 = kk * 32;
        bf16x8 a = *(const bf16x8*)(aptr + k0);
#pragma unroll
        for (int nb = 0; nb < 4; ++nb) {
            const ushort* bptr = Wt + (size_t)(n0 + nb * 16 + rl) * DIM + k0 + kq;
            bf16x8 b = *(const bf16x8*)bptr;
            acc[nb] = __builtin_amdgcn_mfma_f32_16x16x32_bf16(a, b, acc[nb], 0, 0, 0);
        }
    }
    int crow = m0 + (lane >> 4) * 4;
    int ccol = n0 + rl;
#pragma unroll
    for (int nb = 0; nb < 4; ++nb)
#pragma unroll
        for (int r = 0; r < 4; ++r)
            H8[(size_t)(crow + r) * DIM + ccol + nb * 16] = f2fp8(acc[nb][r]);
}

// ---------------- aggregation: async DMA gather (global_load_lds) ----------------
// One wave per dst node; batch of 16 edges staged by 4 global_load_lds_dwordx4:
// instruction q loads 4 rows (lane t=lane>>4 picks edge 4q+t, o=lane&15 picks
// 16 B of that row) -> LDS stage is [16 rows][256 B] contiguous per wave.
// DMA loads consume NO result VGPRs -> the compiler CANNOT re-serialize them
// (the R1-R7 failure mode). 4 KB / 64 lines outstanding per wave, x ~32 waves/CU.
// Edge indices/weights come from ONE coalesced packed-CSR dword + __shfl.
// Lane owns features 4*lane..4*lane+3 end-to-end: no reduce, no LDS atomics.
// mode 0: relu(acc+b) ; mode 1: relu(prev+acc+b) ; mode 2: atomicAdd pooled
__global__ __launch_bounds__(256) void k_agg(
    const unsigned char* __restrict__ H8, const int* __restrict__ row_ptr,
    const unsigned* __restrict__ csr, const float* __restrict__ bias,
    const ushort* __restrict__ prev, ushort* __restrict__ outb,
    float* __restrict__ pooled, const int* __restrict__ batch, int mode) {
    __shared__ uint4 stage[4][256];          // 4 KB per wave: 16 rows x 256 B
    int wave = threadIdx.x >> 6, lane = threadIdx.x & 63;
    int i = blockIdx.x * 4 + wave;           // N_NODES % 4 == 0
    if (i >= N_NODES) return;
    int t = lane >> 4;                       // edge-in-quad 0..3
    int o = lane & 15;                       // 16-B chunk of row
    unsigned char* st = (unsigned char*)&stage[wave][0];

    float a0 = 0.f, a1 = 0.f, a2 = 0.f, a3 = 0.f;
    int e0 = row_ptr[i], e1 = row_ptr[i + 1];   // length >= 1 (self-loop)

    for (int e = e0; e < e1; e += 16) {
        int nb = e1 - e; if (nb > 16) nb = 16;
        // one coalesced CSR load covers the whole batch (lane&15 -> entry e+0..15)
        int ce = e + (lane & 15); if (ce >= e1) ce = e1 - 1;
        unsigned centry = csr[ce];
        // issue 4 DMA gathers (16 rows) back-to-back -- no VGPR destinations
#pragma unroll
        for (int q = 0; q < 4; ++q) {
            unsigned m = __shfl(centry, (q << 2) + t);
            const unsigned char* gp = H8 + (size_t)(m & 0xFFFF) * DIM + o * 16;
            __builtin_amdgcn_global_load_lds(
                (const __attribute__((address_space(1))) unsigned*)gp,
                (__attribute__((address_space(3))) unsigned*)(st + (q << 10)),
                16, 0, 0);
        }
        asm volatile("s_waitcnt vmcnt(0)" ::: "memory");
        // consume staged rows: lane reads its dword (banks 2-way -> free)
        for (int j = 0; j < nb; ++j) {
            unsigned mj = __shfl(centry, j);
            float w = b2f((ushort)(mj >> 16));
            unsigned g = *(const unsigned*)(st + (j << 8) + (lane << 2));
            f32x2 lo = __builtin_amdgcn_cvt_pk_f32_fp8(g, false);
            f32x2 hi = __builtin_amdgcn_cvt_pk_f32_fp8(g, true);
            a0 += w * lo[0]; a1 += w * lo[1]; a2 += w * hi[0]; a3 += w * hi[1];
        }
    }

    int fo = lane * 4;
    const float4 bb = *(const float4*)(bias + fo);
    a0 += bb.x; a1 += bb.y; a2 += bb.z; a3 += bb.w;

    if (mode == 2) {
        int g = batch[i];
        float* p = pooled + (size_t)g * DIM + fo;
        atomicAdd(p + 0, a0); atomicAdd(p + 1, a1);
        atomicAdd(p + 2, a2); atomicAdd(p + 3, a3);
        return;
    }
    if (mode == 1) {
        ushort4 pv = *(const ushort4*)(prev + (size_t)i * DIM + fo);
        a0 += b2f(pv.x); a1 += b2f(pv.y); a2 += b2f(pv.z); a3 += b2f(pv.w);
    }
    ushort4 ov;
    ov.x = f2b(fmaxf(a0, 0.f)); ov.y = f2b(fmaxf(a1, 0.f));
    ov.z = f2b(fmaxf(a2, 0.f)); ov.w = f2b(fmaxf(a3, 0.f));
    *(ushort4*)(outb + (size_t)i * DIM + fo) = ov;
}

// ---------------- head: pooled mean -> logits -> log_softmax ----------------
__global__ void k_final(const float* __restrict__ pooled, const int* __restrict__ counts,
                        const float* __restrict__ Wc, const float* __restrict__ bc,
                        float* __restrict__ out) {
    int g = blockIdx.x, lane = threadIdx.x;   // 64 threads = 1 wave
    float inv = 1.0f / fmaxf((float)counts[g], 1.0f);
    const float4 pv = *(const float4*)(pooled + (size_t)g * DIM + lane * 4);
    float p0 = pv.x * inv, p1 = pv.y * inv, p2 = pv.z * inv, p3 = pv.w * inv;
    __shared__ float logits[N_CLASSES];
    int f = lane * 4;
    for (int c = 0; c < N_CLASSES; ++c) {
        float part = p0 * Wc[(f + 0) * N_CLASSES + c] + p1 * Wc[(f + 1) * N_CLASSES + c]
                   + p2 * Wc[(f + 2) * N_CLASSES + c] + p3 * Wc[(f + 3) * N_CLASSES + c];
        for (int s = 32; s > 0; s >>= 1) part += __shfl_down(part, s);
        if (lane == 0) logits[c] = part + bc[c];
    }
    __syncthreads();
    if (lane == 0) {
        float mx = logits[0];
        for (int c = 1; c < N_CLASSES; ++c) mx = fmaxf(mx, logits[c]);
        float se = 0.f;
        for (int c = 0; c < N_CLASSES; ++c) se += expf(logits[c] - mx);
        float lse = mx + logf(se);
        for (int c = 0; c < N_CLASSES; ++c) {
            out[g * N_CLASSES + c] = logits[c];
            out[N_GRAPHS * N_CLASSES + g * N_CLASSES + c] = logits[c] - lse;
        }
    }
}

// ---------------- launch ----------------
extern "C" void kernel_launch(void* const* d_in, const int* in_sizes, int n_in,
                              void* d_out, int out_size, void* d_ws, size_t ws_size,
                              hipStream_t stream) {
    const float* x    = (const float*)d_in[0];
    const int*   ei   = (const int*)d_in[1];
    const int*   src  = ei;
    const int*   dst  = ei + N_EDGES;
    const int*   batch= (const int*)d_in[2];
    const float* W1 = (const float*)d_in[3]; const float* b1 = (const float*)d_in[4];
    const float* W2 = (const float*)d_in[5]; const float* b2 = (const float*)d_in[6];
    const float* W3 = (const float*)d_in[7]; const float* b3 = (const float*)d_in[8];
    const float* Wc = (const float*)d_in[9]; const float* bc = (const float*)d_in[10];
    float* out = (float*)d_out;

    char* ws = (char*)d_ws;
    size_t off = 0;
    auto alloc = [&](size_t bytes) -> char* {
        char* p = ws + off;
        off = (off + bytes + 255) & ~(size_t)255;
        return p;
    };
    // ---- zeroed region (one memset) ----
    int*      deg     = (int*)alloc(N_NODES * 4);
    int*      fill    = (int*)alloc(N_NODES * 4);
    int*      counts  = (int*)alloc(N_GRAPHS * 4);
    float*    pooled  = (float*)alloc(N_GRAPHS * DIM * 4);
    size_t    zero_bytes = off;
    // ---- uninitialized scratch ----
    unsigned* csr     = (unsigned*)alloc((size_t)CSR_CAP * 4);
    float*  dinv    = (float*)alloc(N_NODES * 4);
    int*    rlen    = (int*)alloc(N_NODES * 4);
    int*    row_ptr = (int*)alloc((N_NODES + 1) * 4);
    ushort* Wt1     = (ushort*)alloc(65536 * 2);
    ushort* Wt2     = (ushort*)alloc(65536 * 2);
    ushort* Wt3     = (ushort*)alloc(65536 * 2);
    ushort* xb      = (ushort*)alloc((size_t)N_NODES * DIM * 2);
    ushort* h1      = (ushort*)alloc((size_t)N_NODES * DIM * 2);
    unsigned char* h8 = (unsigned char*)alloc((size_t)N_NODES * DIM);

    hipMemsetAsync(d_ws, 0, zero_bytes, stream);

    k_convert_x<<<(N_NODES * DIM / 4 + 255) / 256, 256, 0, stream>>>(x, xb, N_NODES * DIM / 4);
    k_wt<<<256, 256, 0, stream>>>(W1, Wt1);
    k_wt<<<256, 256, 0, stream>>>(W2, Wt2);
    k_wt<<<256, 256, 0, stream>>>(W3, Wt3);
    k_deg<<<(N_EDGES + 255) / 256, 256, 0, stream>>>(dst, deg);
    k_counts<<<(N_NODES + 255) / 256, 256, 0, stream>>>(batch, counts);
    k_dinv_len<<<(N_NODES + 255) / 256, 256, 0, stream>>>(deg, dinv, rlen);
    k_scan<<<1, 1024, 0, stream>>>(rlen, row_ptr, N_NODES);
    k_self<<<(N_NODES + 255) / 256, 256, 0, stream>>>(row_ptr, fill, dinv, csr);
    k_fill<<<(N_EDGES + 255) / 256, 256, 0, stream>>>(src, dst, row_ptr, fill, dinv, csr);

    const int agg_grid = N_NODES / 4;   // 5000 blocks, 1 wave per node

    // conv1: h1 = relu(agg(xb @ W1) + b1)
    k_gemm<<<N_NODES / 16, 256, 0, stream>>>(xb, Wt1, h8);
    k_agg<<<agg_grid, 256, 0, stream>>>(h8, row_ptr, csr, b1,
                                        nullptr, h1, nullptr, nullptr, 0);
    // conv2: xb = relu(h1 + agg(h1 @ W2) + b2)
    k_gemm<<<N_NODES / 16, 256, 0, stream>>>(h1, Wt2, h8);
    k_agg<<<agg_grid, 256, 0, stream>>>(h8, row_ptr, csr, b2,
                                        h1, xb, nullptr, nullptr, 1);
    // conv3: pooled += agg(xb @ W3) + b3
    k_gemm<<<N_NODES / 16, 256, 0, stream>>>(xb, Wt3, h8);
    k_agg<<<agg_grid, 256, 0, stream>>>(h8, row_ptr, csr, b3,
                                        nullptr, nullptr, pooled, batch, 2);

    k_final<<<N_GRAPHS, 64, 0, stream>>>(pooled, counts, Wc, bc, out);
}